// Round 1
// 108.582 us; speedup vs baseline: 1.0288x; 1.0288x over previous
//
#include <hip/hip_runtime.h>

// VQ argmin via MFMA: x [16,64,64,64] NCHW fp32, codebook [1024,64] fp32.
// dist = ||e||^2 + (-2x).e  (||x||^2 dropped).  -2x.e computed as bf16 3-way
// split GEMM (h/m/l, keep level-sum<=2 products: hh,hm,mh,hl,mm,lh) -> exact
// to ~2^-26, below fp32 rounding noise.  6 chained MFMAs per k-step.
//
// R9 restructure: R8 (wave = 64 rows x K-quarter) held A-frags 96 VGPR +
// B-dbuf 48 -> ~256 total (AGPR shadow) -> 2 waves/SIMD, MfmaUtil 36%.
// Now: wave = 16 rows x ALL 1024 codes -> A-frags 24 VGPR.  B staged to LDS
// (shared by the 4 waves; per-block L2 traffic unchanged at 384KB) via
// global_load_lds, double-buffered 12KB phases of 32 codes.  4 indep MFMA
// chains x depth 6 per phase.  __launch_bounds__(256,4) -> <=128 VGPR ->
// 4 waves/SIMD.  One __syncthreads per phase; 4 independent blocks/CU hide
// each other's barrier drain.

typedef float f4 __attribute__((ext_vector_type(4)));
typedef short s8v __attribute__((ext_vector_type(8)));
typedef unsigned int u32;

#define D_DIM 64
#define HW    4096
#define ROWS  64
#define INF_  __builtin_inff()
#define MFMA(a,b,c) __builtin_amdgcn_mfma_f32_16x16x32_bf16(a,b,c,0,0,0)

__device__ __forceinline__ unsigned short bf_rne(float f) {
    u32 u = __builtin_bit_cast(u32, f);
    u32 r = u + 0x7fffu + ((u >> 16) & 1u);
    return (unsigned short)(r >> 16);
}
__device__ __forceinline__ float bf_to_f(unsigned short h) {
    u32 u = ((u32)h) << 16;
    return __builtin_bit_cast(float, u);
}
__device__ __forceinline__ void split3(float f, unsigned short& h,
                                       unsigned short& m, unsigned short& l) {
    h = bf_rne(f);
    float f1 = f - bf_to_f(h);
    m = bf_rne(f1);
    float f2 = f1 - bf_to_f(m);
    l = bf_rne(f2);
}
__device__ __forceinline__ s8v pack8(unsigned short a0, unsigned short a1,
                                     unsigned short a2, unsigned short a3,
                                     unsigned short a4, unsigned short a5,
                                     unsigned short a6, unsigned short a7) {
    uint4 u;
    u.x = a0 | ((u32)a1 << 16);
    u.y = a2 | ((u32)a3 << 16);
    u.z = a4 | ((u32)a5 << 16);
    u.w = a6 | ((u32)a7 << 16);
    return __builtin_bit_cast(s8v, u);
}

// ---- prep: split codebook into B-fragment-ordered bf16 h/m/l chunks + enorm.
// Chunk c = T*6 + s*3 + L (T=ntile 0..63, s=kstep, L=level): 64 lanes x 16B.
// lane: code = T*16 + (lane&15), ch = s*32 + (lane>>4)*8 + j  (B[k][n] layout:
// n = lane&15, k = (lane>>4)*8+j).  enorm (fp32, exact) at ws + 384KB.
__global__ __launch_bounds__(64) void prep_kernel(const float* __restrict__ cb,
                                                  char* __restrict__ wsb) {
    const int blk = blockIdx.x;
    const int lane = threadIdx.x;
    if (blk < 384) {
        const int T = blk / 6;
        const int rem = blk - T * 6;
        const int s = rem / 3;
        const int L = rem - s * 3;
        const int code = T * 16 + (lane & 15);
        const int ch0 = s * 32 + (lane >> 4) * 8;
        const float* src = cb + code * 64 + ch0;
        unsigned short o[8];
#pragma unroll
        for (int j = 0; j < 8; ++j) {
            unsigned short h, m2, l;
            split3(src[j], h, m2, l);
            o[j] = (L == 0) ? h : (L == 1) ? m2 : l;
        }
        uint4 w;
        w.x = o[0] | ((u32)o[1] << 16);
        w.y = o[2] | ((u32)o[3] << 16);
        w.z = o[4] | ((u32)o[5] << 16);
        w.w = o[6] | ((u32)o[7] << 16);
        *(uint4*)(wsb + (size_t)blk * 1024 + lane * 16) = w;
    } else {
        const int k = (blk - 384) * 64 + lane;
        const f4* row = (const f4*)(cb + (size_t)k * 64);
        float sacc = 0.f;
#pragma unroll
        for (int i = 0; i < 16; ++i) {
            f4 v = row[i];
            sacc = fmaf(v.x, v.x, sacc);
            sacc = fmaf(v.y, v.y, sacc);
            sacc = fmaf(v.z, v.z, sacc);
            sacc = fmaf(v.w, v.w, sacc);
        }
        ((float*)(wsb + 384 * 1024))[k] = sacc;
    }
}

// async global->LDS, 16B per lane: LDS dest = wave-uniform base + lane*16,
// global src is per-lane (must carry the lane*16 term).
__device__ __forceinline__ void gl_lds16(const char* g, char* l) {
    __builtin_amdgcn_global_load_lds(
        (const __attribute__((address_space(1))) void*)g,
        (__attribute__((address_space(3))) void*)l, 16, 0, 0);
}

// build A-frags of (-2x) for this wave's 16 rows, kstep s
#define BUILD_A(s) { \
    const float* xr = (const float*)&xs4[w16 + m_][0]; \
    f4 va = *(const f4*)(xr + (s) * 32 + ko); \
    f4 vb = *(const f4*)(xr + (s) * 32 + ko + 4); \
    unsigned short h0,h1,h2,h3,h4,h5,h6,h7; \
    unsigned short q0,q1,q2,q3,q4,q5,q6,q7; \
    unsigned short l0,l1,l2,l3,l4,l5,l6,l7; \
    split3(-2.f * va.x, h0, q0, l0); split3(-2.f * va.y, h1, q1, l1); \
    split3(-2.f * va.z, h2, q2, l2); split3(-2.f * va.w, h3, q3, l3); \
    split3(-2.f * vb.x, h4, q4, l4); split3(-2.f * vb.y, h5, q5, l5); \
    split3(-2.f * vb.z, h6, q6, l6); split3(-2.f * vb.w, h7, q7, l7); \
    Ah##s = pack8(h0,h1,h2,h3,h4,h5,h6,h7); \
    Am##s = pack8(q0,q1,q2,q3,q4,q5,q6,q7); \
    Al##s = pack8(l0,l1,l2,l3,l4,l5,l6,l7); \
}

#define UPD1(t, i, en, kn) { \
    float v = a##t##a[i] + a##t##b[i] + (en); \
    bool pr = (v < best##i); \
    best##i = pr ? v : best##i; \
    idx##i  = pr ? (kn) : idx##i; \
}

#define Z4 (f4){0.f,0.f,0.f,0.f}

// one phase = 2 code-tiles (32 codes).  Stage next phase (3 chunks/wave) into
// buf CUR^1; ds_read 12 B-frags from buf CUR; 24 MFMAs as 4 indep chains
// (tile0/tile1 x kstep0/kstep1) x depth 6; argmin-update; one barrier.
#define PHASE(CUR, P) { \
    const char* gsrc = wsb + (size_t)(((P) + 1) & 31) * 12288 + stageoff; \
    char* ldst = sB + (((CUR) ^ 1) * 12288) + w3072; \
    gl_lds16(gsrc,        ldst); \
    gl_lds16(gsrc + 1024, ldst + 1024); \
    gl_lds16(gsrc + 2048, ldst + 2048); \
    const char* bb = sB + (CUR) * 12288 + lane16; \
    s8v B0h0 = *(const s8v*)(bb +     0), B0m0 = *(const s8v*)(bb +  1024); \
    s8v B0l0 = *(const s8v*)(bb +  2048), B0h1 = *(const s8v*)(bb +  3072); \
    s8v B0m1 = *(const s8v*)(bb +  4096), B0l1 = *(const s8v*)(bb +  5120); \
    s8v B1h0 = *(const s8v*)(bb +  6144), B1m0 = *(const s8v*)(bb +  7168); \
    s8v B1l0 = *(const s8v*)(bb +  8192), B1h1 = *(const s8v*)(bb +  9216); \
    s8v B1m1 = *(const s8v*)(bb + 10240), B1l1 = *(const s8v*)(bb + 11264); \
    const float en0 = sEn[(P) * 32 + m_]; \
    const float en1 = sEn[(P) * 32 + 16 + m_]; \
    f4 a0a = Z4, a0b = Z4, a1a = Z4, a1b = Z4; \
    a0a = MFMA(Ah0,B0h0,a0a); a0b = MFMA(Ah1,B0h1,a0b); \
    a1a = MFMA(Ah0,B1h0,a1a); a1b = MFMA(Ah1,B1h1,a1b); \
    a0a = MFMA(Ah0,B0m0,a0a); a0b = MFMA(Ah1,B0m1,a0b); \
    a1a = MFMA(Ah0,B1m0,a1a); a1b = MFMA(Ah1,B1m1,a1b); \
    a0a = MFMA(Am0,B0h0,a0a); a0b = MFMA(Am1,B0h1,a0b); \
    a1a = MFMA(Am0,B1h0,a1a); a1b = MFMA(Am1,B1h1,a1b); \
    a0a = MFMA(Ah0,B0l0,a0a); a0b = MFMA(Ah1,B0l1,a0b); \
    a1a = MFMA(Ah0,B1l0,a1a); a1b = MFMA(Ah1,B1l1,a1b); \
    a0a = MFMA(Am0,B0m0,a0a); a0b = MFMA(Am1,B0m1,a0b); \
    a1a = MFMA(Am0,B1m0,a1a); a1b = MFMA(Am1,B1m1,a1b); \
    a0a = MFMA(Al0,B0h0,a0a); a0b = MFMA(Al1,B0h1,a0b); \
    a1a = MFMA(Al0,B1h0,a1a); a1b = MFMA(Al1,B1h1,a1b); \
    const int kn0 = (P) * 32 + m_; \
    UPD1(0,0,en0,kn0)    UPD1(0,1,en0,kn0)    UPD1(0,2,en0,kn0)    UPD1(0,3,en0,kn0) \
    UPD1(1,0,en1,kn0+16) UPD1(1,1,en1,kn0+16) UPD1(1,2,en1,kn0+16) UPD1(1,3,en1,kn0+16) \
    __syncthreads(); \
}

#define BF1(i, msk) { \
    float ov = __shfl_xor(best##i, msk); \
    int   oi = __shfl_xor(idx##i,  msk); \
    bool pr = (ov < best##i) || (ov == best##i && oi < idx##i); \
    best##i = pr ? ov : best##i; \
    idx##i  = pr ? oi : idx##i; \
}
#define BFALL(msk) BF1(0,msk) BF1(1,msk) BF1(2,msk) BF1(3,msk)

__global__ __launch_bounds__(256, 4) void vq_kernel(const float* __restrict__ x,
                                                    const char* __restrict__ wsb,
                                                    int* __restrict__ out) {
    // union: xs4[64][17] f4 (17408B) lives here until A-build done, then the
    // same region becomes the 2x12288B B staging buffers.
    __shared__ __align__(16) char smem[24576];
    __shared__ float sEn[1024];
    f4 (*xs4)[17] = (f4 (*)[17])smem;
    char* const sB = smem;

    const int tid = threadIdx.x;
    const int lane = tid & 63;
    const int w = __builtin_amdgcn_readfirstlane(tid >> 6);   // wave id 0..3
    const int m_ = lane & 15;
    const int ko = (lane >> 4) * 8;
    const int w16 = w * 16;
    const int w3072 = w * 3072;
    const int lane16 = lane * 16;
    const int stageoff = w3072 + lane16;
    const int n0 = blockIdx.x * ROWS;
    const int b = n0 >> 12;
    const int hw0 = n0 & (HW - 1);

    // stage e-norms
    const float* enp = (const float*)(wsb + 384 * 1024);
#pragma unroll
    for (int q = 0; q < 4; ++q) sEn[q * 256 + tid] = enp[q * 256 + tid];

    // stage x tile (fp32): wave w loads channels w*16..w*16+15 of all 64 rows
    {
        const float* g = x + ((size_t)b * D_DIM + w16) * HW + hw0 + lane;
        float v[16];
#pragma unroll
        for (int i = 0; i < 16; ++i) v[i] = g[(size_t)i * HW];
#pragma unroll
        for (int j = 0; j < 4; ++j)
            xs4[lane][w * 4 + j] = (f4){v[4*j], v[4*j+1], v[4*j+2], v[4*j+3]};
    }
    __syncthreads();

    // build A frags of (-2x) for THIS wave's 16 rows: 2 ksteps x 3 levels
    s8v Ah0, Am0, Al0, Ah1, Am1, Al1;
    BUILD_A(0) BUILD_A(1)
    __syncthreads();          // all waves done with xs4 -> smem becomes sB

    // stage phase 0 into buf0
    {
        const char* g0 = wsb + stageoff;
        char* l0 = sB + w3072;
        gl_lds16(g0,        l0);
        gl_lds16(g0 + 1024, l0 + 1024);
        gl_lds16(g0 + 2048, l0 + 2048);
    }

    float best0 = INF_, best1 = INF_, best2 = INF_, best3 = INF_;
    int idx0 = 0, idx1 = 0, idx2 = 0, idx3 = 0;
    __syncthreads();          // phase-0 staging complete (vmcnt drained)

#pragma unroll 1
    for (int pp = 0; pp < 16; ++pp) {
        PHASE(0, pp * 2)
        PHASE(1, pp * 2 + 1)
    }

    // per-row argmin across the 16 code-classes in each 16-lane group
    BFALL(1) BFALL(2) BFALL(4) BFALL(8)

    // lane m_==0 of each group holds rows (lane>>4)*4 .. +3 of this wave's
    // 16-row stripe; write 4 contiguous indices as int4
    if (m_ == 0) {
        int4 o4; o4.x = idx0; o4.y = idx1; o4.z = idx2; o4.w = idx3;
        *(int4*)(out + n0 + w16 + (lane >> 4) * 4) = o4;
    }
}

extern "C" void kernel_launch(void* const* d_in, const int* in_sizes, int n_in,
                              void* d_out, int out_size, void* d_ws, size_t ws_size,
                              hipStream_t stream) {
    const float* x  = (const float*)d_in[0];   // [16,64,64,64] fp32
    const float* cb = (const float*)d_in[1];   // [1024,64] fp32
    char* wsb = (char*)d_ws;                   // 384KB packed cb + 4KB enorm
    int*  out = (int*)d_out;                   // 65536 int32 indices

    prep_kernel<<<dim3(400), dim3(64), 0, stream>>>(cb, wsb);
    vq_kernel<<<dim3(65536 / ROWS), dim3(256), 0, stream>>>(x, wsb, out);
}